// Round 6
// baseline (26.245 us; speedup 1.0000x reference)
//
#include <hip/hip_runtime.h>
#include <math.h>

#define ROWS 32
#define LROW 15104
#define TWIN 128
#define NWIN 118
#define TRIM 14848               // LROW - 2*TWIN
#define NW   (ROWS * NWIN)       // 3776 real windows
#define WPB  7                   // windows per block (waves 1..7)
#define BPR  17                  // 17*7 = 119 >= 118 (1 masked)
#define NBLK (ROWS * BPR)        // 544 = 8 * 68  (bijective XCD chunks)
#define YPAN ((WPB + 2) * TWIN)  // 1152 floats, unscaled y panel

__device__ __forceinline__ float readlane_f(float v, int lane) {
    return __int_as_float(__builtin_amdgcn_readlane(__float_as_int(v), lane));
}

// ---- fused: wave 0 = row stats (VMEM) ; waves 1..7 = 7 windows (LDS+VALU) ----
__global__ __launch_bounds__(512) void loss_fused(
        const float* __restrict__ data,
        const float* __restrict__ target,
        float* __restrict__ blocksums) {
    // XCD-chunked swizzle: 68 consecutive logical blocks (= 4 full rows) per XCD.
    int b0 = blockIdx.x;
    int b  = (b0 & 7) * (NBLK / 8) + (b0 >> 3);
    int row = b / BPR;
    int n0  = (b % BPR) * WPB;
    int tid  = threadIdx.x;
    int wave = tid >> 6;
    int lane = tid & 63;

    __shared__ float ys[YPAN];
    __shared__ float wl[8];
    __shared__ float s_scale2;

    const float* xrow = data   + row * LROW;
    const float* rrow = target + row * LROW;

    int  n     = n0 + wave - 1;                 // window for waves 1..7
    bool valid = (wave >= 1) && (n < NWIN);

    // ---- issue x register loads early (global, coalesced float2/lane) ----
    float xa = 0.f, xb = 0.f;
    if (valid) {
        float2 v = *(const float2*)(xrow + n * TWIN + 2 * lane);
        xa = v.x; xb = v.y;
    }

    // ---- stage UNSCALED y panel: [(n0-1)*128, (n0+8)*128) with zero pad ----
    for (int j = tid; j < YPAN / 4; j += 512) {
        int g = (n0 - 1) * TWIN + 4 * j;
        float4 v = make_float4(0.f, 0.f, 0.f, 0.f);
        if (g >= 0 && g < LROW) v = *(const float4*)(rrow + g);
        *(float4*)&ys[4 * j] = v;
    }
    __syncthreads();

    float lmin = 0.f;           // masked waves / wave 0 contribute 0

    if (wave == 0) {
        // ---- row stats on the VMEM pipe, concurrent with correlation ----
        const float4* x4 = (const float4*)(xrow + TWIN);
        const float4* r4 = (const float4*)(rrow + TWIN);
        float sd = 0.f, sd2 = 0.f, sr = 0.f, sr2 = 0.f;
        for (int i = lane; i < TRIM / 4; i += 64) {   // 58 iters
            float4 a = x4[i], bv = r4[i];
            sd  += a.x + a.y + a.z + a.w;
            sd2 += a.x*a.x + a.y*a.y + a.z*a.z + a.w*a.w;
            sr  += bv.x + bv.y + bv.z + bv.w;
            sr2 += bv.x*bv.x + bv.y*bv.y + bv.z*bv.z + bv.w*bv.w;
        }
        #pragma unroll
        for (int off = 32; off > 0; off >>= 1) {
            sd  += __shfl_xor(sd,  off, 64);
            sd2 += __shfl_xor(sd2, off, 64);
            sr  += __shfl_xor(sr,  off, 64);
            sr2 += __shfl_xor(sr2, off, 64);
        }
        if (lane == 0) {
            const float inv = 1.0f / (float)TRIM;
            float md = sd * inv, mr = sr * inv;
            float vx = fmaxf(sd2 * inv - md * md, 0.f);
            float vr = fmaxf(sr2 * inv - mr * mr, 0.f);
            float mag_x = sqrtf(vx), mag_r = sqrtf(vr);
            float mag_min = fminf(mag_x, mag_r);
            float scale = 1.0f / (sqrtf(mag_min * mag_r) + 0.001f);
            s_scale2 = scale * scale;
        }
    } else if (valid) {
        // ---- raw (unscaled) correlation sums for window n ----
        const float*  yw  = ys + (wave - 1) * TWIN;    // 384-float view
        const float4* ys4 = (const float4*)yw;

        // cooperative: sx = sum x^2 ; s=256 raw sum of squared diffs
        float sx, part;
        {
            float2 yv = *(const float2*)(yw + 256 + 2 * lane);
            float d0 = xa - yv.x, d1 = xb - yv.y;
            part = d0 * d0 + d1 * d1;
            sx   = xa * xa + xb * xb;
            #pragma unroll
            for (int off = 32; off > 0; off >>= 1) {
                part += __shfl_xor(part, off, 64);
                sx   += __shfl_xor(sx,   off, 64);
            }
        }

        // shifts s0..s0+3, s0 = 4*lane (covers s=0..255)
        float4 yv0 = ys4[lane];
        float yf0 = yv0.x, yf1 = yv0.y, yf2 = yv0.z;
        float c0 = 0.f, c1 = 0.f, c2 = 0.f, c3 = 0.f;
        float q = 0.f;

        #pragma unroll
        for (int kb = 0; kb < 32; ++kb) {
            // x[4kb..4kb+3] broadcast from registers (VALU, no LDS)
            float x0 = readlane_f(xa, 2 * kb);
            float x1 = readlane_f(xb, 2 * kb);
            float x2 = readlane_f(xa, 2 * kb + 1);
            float x3 = readlane_f(xb, 2 * kb + 1);
            float4 yv1 = ys4[lane + kb + 1];
            c0 += x0*yv0.x + x1*yv0.y + x2*yv0.z + x3*yv0.w;
            c1 += x0*yv0.y + x1*yv0.z + x2*yv0.w + x3*yv1.x;
            c2 += x0*yv0.z + x1*yv0.w + x2*yv1.x + x3*yv1.y;
            c3 += x0*yv0.w + x1*yv1.x + x2*yv1.y + x3*yv1.z;
            q  += yv0.x*yv0.x + yv0.y*yv0.y + yv0.z*yv0.z + yv0.w*yv0.w;
            yv0 = yv1;
        }
        // yv0 = y[s0+128 .. s0+131]
        float sy0 = q;
        float sy1 = sy0 - yf0*yf0 + yv0.x*yv0.x;
        float sy2 = sy1 - yf1*yf1 + yv0.y*yv0.y;
        float sy3 = sy2 - yf2*yf2 + yv0.z*yv0.z;

        // stash raw sums; scale applied after barrier
        // (kept in regs: c0..c3, sy0..sy3, sx, part)
        __syncthreads();                 // wave 0 published s_scale2
        float scale2 = s_scale2;

        const float inv = 1.0f / (float)TWIN;
        int   s0  = lane * 4;
        lmin = 1e30f;
        {
            float mse, ph, cp, bw, w;
            mse = scale2 * (sx - 2.f*c0 + sy0) * inv;
            ph  = (float)(s0 + 0) * (float)(M_PI / 128.0);
            cp  = __cosf(ph); bw = 0.42f - 0.5f*cp + 0.08f*(2.f*cp*cp - 1.f);
            w   = 100.f * (1.f - bw);
            lmin = fminf(lmin, (mse + 1.f) * (w + 1.f) - 1.f);
            mse = scale2 * (sx - 2.f*c1 + sy1) * inv;
            ph  = (float)(s0 + 1) * (float)(M_PI / 128.0);
            cp  = __cosf(ph); bw = 0.42f - 0.5f*cp + 0.08f*(2.f*cp*cp - 1.f);
            w   = 100.f * (1.f - bw);
            lmin = fminf(lmin, (mse + 1.f) * (w + 1.f) - 1.f);
            mse = scale2 * (sx - 2.f*c2 + sy2) * inv;
            ph  = (float)(s0 + 2) * (float)(M_PI / 128.0);
            cp  = __cosf(ph); bw = 0.42f - 0.5f*cp + 0.08f*(2.f*cp*cp - 1.f);
            w   = 100.f * (1.f - bw);
            lmin = fminf(lmin, (mse + 1.f) * (w + 1.f) - 1.f);
            mse = scale2 * (sx - 2.f*c3 + sy3) * inv;
            ph  = (float)(s0 + 3) * (float)(M_PI / 128.0);
            cp  = __cosf(ph); bw = 0.42f - 0.5f*cp + 0.08f*(2.f*cp*cp - 1.f);
            w   = 100.f * (1.f - bw);
            lmin = fminf(lmin, (mse + 1.f) * (w + 1.f) - 1.f);
        }
        // s = 256: w = 100 exactly
        lmin = fminf(lmin, (scale2 * part * inv + 1.f) * 101.f - 1.f);
        #pragma unroll
        for (int off = 32; off > 0; off >>= 1)
            lmin = fminf(lmin, __shfl_xor(lmin, off, 64));
    }

    // waves that skipped the inner block (wave 0 / masked) still hit this
    // barrier exactly once: the valid-branch consumed its own __syncthreads.
    if (wave == 0 || !valid) __syncthreads();

    if (lane == 0) wl[wave] = lmin;
    __syncthreads();
    if (tid == 0) {
        float s = 0.f;
        #pragma unroll
        for (int i = 1; i < 8; ++i) s += wl[i];   // fixed order, wave0 excluded
        blocksums[b] = s;
    }
}

// ---------------- final mean ----------------
__global__ __launch_bounds__(256) void finish_kernel(
        const float* __restrict__ blocksums,
        float* __restrict__ out) {
    int tid = threadIdx.x;
    float s = 0.f;
    for (int i = tid; i < NBLK; i += 256) s += blocksums[i];
    __shared__ float sh[256];
    sh[tid] = s;
    __syncthreads();
    for (int off = 128; off > 0; off >>= 1) {
        if (tid < off) sh[tid] += sh[tid + off];
        __syncthreads();
    }
    if (tid == 0) out[0] = sh[0] / (float)NW;
}

extern "C" void kernel_launch(void* const* d_in, const int* in_sizes, int n_in,
                              void* d_out, int out_size, void* d_ws, size_t ws_size,
                              hipStream_t stream) {
    const float* data   = (const float*)d_in[0];
    const float* target = (const float*)d_in[1];
    float* blocksums = (float*)d_ws;

    loss_fused<<<NBLK, 512, 0, stream>>>(data, target, blocksums);
    finish_kernel<<<1, 256, 0, stream>>>(blocksums, (float*)d_out);
}

// Round 7
// 17.226 us; speedup vs baseline: 1.5236x; 1.5236x over previous
//
#include <hip/hip_runtime.h>
#include <math.h>

#define ROWS 32
#define LROW 15104
#define TWIN 128
#define NWIN 118
#define TRIM 14848              // LROW - 2*TWIN
#define NW   (ROWS * NWIN)      // 3776 real windows
#define WPB  8                  // windows per block (one per wave)
#define BPR  15                 // 8*15 = 120 >= 118 (2 masked)
#define NBLK (ROWS * BPR)       // 480 = 8 * 60 (bijective XCD chunks)
#define YPAN (10 * TWIN)        // 1280 floats: [(n0-1)*128, (n0+9)*128)

// ---------------- fused: row stats + shifted-L2 over 8 windows ----------------
__global__ __launch_bounds__(512) void loss_fused(
        const float* __restrict__ data,
        const float* __restrict__ target,
        float* __restrict__ blocksums) {
    // XCD-chunked swizzle: 60 consecutive logical blocks (= 4 rows) per XCD.
    int b0 = blockIdx.x;
    int b  = (b0 & 7) * (NBLK / 8) + (b0 >> 3);
    int row = b / BPR;
    int n0  = (b % BPR) * WPB;
    int tid  = threadIdx.x;
    int wave = tid >> 6;
    int lane = tid & 63;

    __shared__ float  ys[YPAN];
    __shared__ float4 wsum[8];
    __shared__ float  wl[8];

    const float* xrow = data   + row * LROW;
    const float* rrow = target + row * LROW;

    // ---- Phase 1: stats partial sums (all 8 waves share the row scan) ----
    float sd = 0.f, sd2 = 0.f, sr = 0.f, sr2 = 0.f;
    {
        const float4* x4 = (const float4*)(xrow + TWIN);
        const float4* r4 = (const float4*)(rrow + TWIN);
        for (int i = tid; i < TRIM / 4; i += 512) {
            float4 a = x4[i], bv = r4[i];
            sd  += a.x + a.y + a.z + a.w;
            sd2 += a.x*a.x + a.y*a.y + a.z*a.z + a.w*a.w;
            sr  += bv.x + bv.y + bv.z + bv.w;
            sr2 += bv.x*bv.x + bv.y*bv.y + bv.z*bv.z + bv.w*bv.w;
        }
        #pragma unroll
        for (int off = 32; off > 0; off >>= 1) {
            sd  += __shfl_xor(sd,  off, 64);
            sd2 += __shfl_xor(sd2, off, 64);
            sr  += __shfl_xor(sr,  off, 64);
            sr2 += __shfl_xor(sr2, off, 64);
        }
        if (lane == 0) wsum[wave] = make_float4(sd, sd2, sr, sr2);
    }

    // ---- Phase 2: stage UNSCALED y panel ----
    for (int j = tid; j < YPAN / 4; j += 512) {
        int g = (n0 - 1) * TWIN + 4 * j;
        float4 v = make_float4(0.f, 0.f, 0.f, 0.f);
        if (g >= 0 && g < LROW) v = *(const float4*)(rrow + g);
        *(float4*)&ys[4 * j] = v;
    }
    __syncthreads();    // ys + wsum visible

    // ---- Phase 3: every thread combines wsum -> scale^2 (no 2nd barrier) ----
    float scale2;
    {
        float td = 0.f, td2 = 0.f, tr = 0.f, tr2 = 0.f;
        #pragma unroll
        for (int i = 0; i < 8; ++i) {
            float4 p = wsum[i];
            td += p.x; td2 += p.y; tr += p.z; tr2 += p.w;
        }
        const float inv = 1.0f / (float)TRIM;
        float md = td * inv, mr = tr * inv;
        float vx = fmaxf(td2 * inv - md * md, 0.f);
        float vr = fmaxf(tr2 * inv - mr * mr, 0.f);
        float mag_x = sqrtf(vx), mag_r = sqrtf(vr);
        float mag_min = fminf(mag_x, mag_r);
        float scale = 1.0f / (sqrtf(mag_min * mag_r) + 0.001f);
        scale2 = scale * scale;
    }

    // ---- Phase 4: wave computes window n0+wave on raw data ----
    int  n     = n0 + wave;
    bool valid = (n < NWIN);
    int  nu    = __builtin_amdgcn_readfirstlane(valid ? n : NWIN - 1);
    const float* xw = xrow + nu * TWIN;          // wave-uniform (SGPR) pointer
    const float* yw = ys + wave * TWIN;          // 384-float LDS view

    // cooperative: sx = sum x^2 ; s=256 raw sum of squared diffs
    float sx, part;
    {
        float xa = xw[lane], xb = xw[lane + 64];
        float ya = yw[256 + lane], yb = yw[320 + lane];
        float d0 = xa - ya, d1 = xb - yb;
        part = d0 * d0 + d1 * d1;
        sx   = xa * xa + xb * xb;
        #pragma unroll
        for (int off = 32; off > 0; off >>= 1) {
            part += __shfl_xor(part, off, 64);
            sx   += __shfl_xor(sx,   off, 64);
        }
    }

    const float4* ys4 = (const float4*)yw;

    // shifts s0..s0+3, s0 = 4*lane (covers s=0..255)
    float4 yv0 = ys4[lane];
    float yf0 = yv0.x, yf1 = yv0.y, yf2 = yv0.z;
    float c0 = 0.f, c1 = 0.f, c2 = 0.f, c3 = 0.f;
    float q = 0.f;

    #pragma unroll
    for (int kb = 0; kb < 32; ++kb) {
        float4 xv  = *(const float4*)(xw + 4 * kb);  // uniform-addr broadcast
        float4 yv1 = ys4[lane + kb + 1];             // the only LDS read
        c0 += xv.x*yv0.x + xv.y*yv0.y + xv.z*yv0.z + xv.w*yv0.w;
        c1 += xv.x*yv0.y + xv.y*yv0.z + xv.z*yv0.w + xv.w*yv1.x;
        c2 += xv.x*yv0.z + xv.y*yv0.w + xv.z*yv1.x + xv.w*yv1.y;
        c3 += xv.x*yv0.w + xv.y*yv1.x + xv.z*yv1.y + xv.w*yv1.z;
        q  += yv0.x*yv0.x + yv0.y*yv0.y + yv0.z*yv0.z + yv0.w*yv0.w;
        yv0 = yv1;
    }
    // yv0 = y[s0+128 .. s0+131]
    float sy0 = q;
    float sy1 = sy0 - yf0*yf0 + yv0.x*yv0.x;
    float sy2 = sy1 - yf1*yf1 + yv0.y*yv0.y;
    float sy3 = sy2 - yf2*yf2 + yv0.z*yv0.z;

    const float inv = 1.0f / (float)TWIN;
    int   s0  = lane * 4;
    float lmin = 1e30f;
    {
        float mse, ph, cp, bw, w;
        mse = scale2 * (sx - 2.f*c0 + sy0) * inv;
        ph  = (float)(s0 + 0) * (float)(M_PI / 128.0);
        cp  = __cosf(ph); bw = 0.42f - 0.5f*cp + 0.08f*(2.f*cp*cp - 1.f);
        w   = 100.f * (1.f - bw);
        lmin = fminf(lmin, (mse + 1.f) * (w + 1.f) - 1.f);
        mse = scale2 * (sx - 2.f*c1 + sy1) * inv;
        ph  = (float)(s0 + 1) * (float)(M_PI / 128.0);
        cp  = __cosf(ph); bw = 0.42f - 0.5f*cp + 0.08f*(2.f*cp*cp - 1.f);
        w   = 100.f * (1.f - bw);
        lmin = fminf(lmin, (mse + 1.f) * (w + 1.f) - 1.f);
        mse = scale2 * (sx - 2.f*c2 + sy2) * inv;
        ph  = (float)(s0 + 2) * (float)(M_PI / 128.0);
        cp  = __cosf(ph); bw = 0.42f - 0.5f*cp + 0.08f*(2.f*cp*cp - 1.f);
        w   = 100.f * (1.f - bw);
        lmin = fminf(lmin, (mse + 1.f) * (w + 1.f) - 1.f);
        mse = scale2 * (sx - 2.f*c3 + sy3) * inv;
        ph  = (float)(s0 + 3) * (float)(M_PI / 128.0);
        cp  = __cosf(ph); bw = 0.42f - 0.5f*cp + 0.08f*(2.f*cp*cp - 1.f);
        w   = 100.f * (1.f - bw);
        lmin = fminf(lmin, (mse + 1.f) * (w + 1.f) - 1.f);
    }
    // s = 256: w[256] = 100 exactly
    lmin = fminf(lmin, (scale2 * part * inv + 1.f) * 101.f - 1.f);

    #pragma unroll
    for (int off = 32; off > 0; off >>= 1)
        lmin = fminf(lmin, __shfl_xor(lmin, off, 64));

    if (!valid) lmin = 0.f;                // masked windows contribute 0

    if (lane == 0) wl[wave] = lmin;
    __syncthreads();
    if (tid == 0) {
        float s = 0.f;
        #pragma unroll
        for (int i = 0; i < 8; ++i) s += wl[i];   // fixed order: deterministic
        blocksums[b] = s;
    }
}

// ---------------- final mean ----------------
__global__ __launch_bounds__(256) void finish_kernel(
        const float* __restrict__ blocksums,
        float* __restrict__ out) {
    int tid = threadIdx.x;
    float s = 0.f;
    for (int i = tid; i < NBLK; i += 256) s += blocksums[i];
    __shared__ float sh[256];
    sh[tid] = s;
    __syncthreads();
    for (int off = 128; off > 0; off >>= 1) {
        if (tid < off) sh[tid] += sh[tid + off];
        __syncthreads();
    }
    if (tid == 0) out[0] = sh[0] / (float)NW;
}

extern "C" void kernel_launch(void* const* d_in, const int* in_sizes, int n_in,
                              void* d_out, int out_size, void* d_ws, size_t ws_size,
                              hipStream_t stream) {
    const float* data   = (const float*)d_in[0];
    const float* target = (const float*)d_in[1];
    float* blocksums = (float*)d_ws;

    loss_fused<<<NBLK, 512, 0, stream>>>(data, target, blocksums);
    finish_kernel<<<1, 256, 0, stream>>>(blocksums, (float*)d_out);
}